// Round 2
// baseline (15497.766 us; speedup 1.0000x reference)
//
#include <hip/hip_runtime.h>
#include <math.h>

#define C 512
#define NPIX 4096   // H*W
#define BATCH 8
#define EPS 1e-5f

// bf16 <-> f32 helpers (RNE, no NaN handling needed for our data)
static __device__ __forceinline__ unsigned short f2bf(float f) {
    union { float f; unsigned int u; } a; a.f = f;
    unsigned int r = a.u + 0x7FFFu + ((a.u >> 16) & 1u);
    return (unsigned short)(r >> 16);
}
static __device__ __forceinline__ float bf2f(unsigned short h) {
    union { unsigned int u; float f; } a; a.u = ((unsigned int)h) << 16;
    return a.f;
}

// ---------------------------------------------------------------------------
// Kernel 1: fused qk+v conv1x1 GEMM + BN + SiLU.
//   o in [0,1536): 0..1023 -> qk (bf16 out), 1024.. -> v (f32 out)
// ---------------------------------------------------------------------------
__global__ __launch_bounds__(256) void k_qkv(
    const float* __restrict__ x,
    const float* __restrict__ qk_w, const float* __restrict__ qk_g,
    const float* __restrict__ qk_b, const float* __restrict__ qk_rm,
    const float* __restrict__ qk_rv,
    const float* __restrict__ v_w, const float* __restrict__ v_g,
    const float* __restrict__ v_b, const float* __restrict__ v_rm,
    const float* __restrict__ v_rv,
    unsigned short* __restrict__ qk_out, float* __restrict__ v_out)
{
    __shared__ float As[16][65];   // [k][o], padded
    __shared__ float Bs[16][64];   // [k][n]
    const int t  = threadIdx.x;
    const int tx = t & 15, ty = t >> 4;
    const int tx4 = tx * 4, ty4 = ty * 4;
    const int nb = blockIdx.x * 64;
    const int ob = blockIdx.y * 64;
    const int b  = blockIdx.z;
    const float* xb = x + (size_t)b * C * NPIX;

    float acc[4][4] = {};

    for (int k0 = 0; k0 < C; k0 += 16) {
        #pragma unroll
        for (int e = 0; e < 4; ++e) {
            int idx = e * 256 + t;
            int kl = idx & 15, ol = idx >> 4;
            int o = ob + ol;
            As[kl][ol] = (o < 1024) ? qk_w[(size_t)o * C + k0 + kl]
                                    : v_w[(size_t)(o - 1024) * C + k0 + kl];
        }
        #pragma unroll
        for (int e = 0; e < 4; ++e) {
            int idx = e * 256 + t;
            int nl = idx & 63, kl = idx >> 6;
            Bs[kl][nl] = xb[(size_t)(k0 + kl) * NPIX + nb + nl];
        }
        __syncthreads();
        #pragma unroll
        for (int kk = 0; kk < 16; ++kk) {
            const float a0 = As[kk][ty4 + 0];
            const float a1 = As[kk][ty4 + 1];
            const float a2 = As[kk][ty4 + 2];
            const float a3 = As[kk][ty4 + 3];
            const float4 bq = *(const float4*)&Bs[kk][tx4];
            acc[0][0] += a0 * bq.x; acc[0][1] += a0 * bq.y; acc[0][2] += a0 * bq.z; acc[0][3] += a0 * bq.w;
            acc[1][0] += a1 * bq.x; acc[1][1] += a1 * bq.y; acc[1][2] += a1 * bq.z; acc[1][3] += a1 * bq.w;
            acc[2][0] += a2 * bq.x; acc[2][1] += a2 * bq.y; acc[2][2] += a2 * bq.z; acc[2][3] += a2 * bq.w;
            acc[3][0] += a3 * bq.x; acc[3][1] += a3 * bq.y; acc[3][2] += a3 * bq.z; acc[3][3] += a3 * bq.w;
        }
        __syncthreads();
    }

    #pragma unroll
    for (int i = 0; i < 4; ++i) {
        int o = ob + ty4 + i;
        if (o < 1024) {
            const float sc = qk_g[o] * rsqrtf(qk_rv[o] + EPS);
            const float rm = qk_rm[o], bb = qk_b[o];
            unsigned short* dst = qk_out + ((size_t)b * 1024 + o) * NPIX + nb;
            ushort4 r;
            float y;
            y = (acc[i][0] - rm) * sc + bb; r.x = f2bf(y / (1.0f + expf(-y)));
            y = (acc[i][1] - rm) * sc + bb; r.y = f2bf(y / (1.0f + expf(-y)));
            y = (acc[i][2] - rm) * sc + bb; r.z = f2bf(y / (1.0f + expf(-y)));
            y = (acc[i][3] - rm) * sc + bb; r.w = f2bf(y / (1.0f + expf(-y)));
            *(ushort4*)&dst[tx4] = r;
        } else {
            int oo = o - 1024;
            const float sc = v_g[oo] * rsqrtf(v_rv[oo] + EPS);
            const float rm = v_rm[oo], bb = v_b[oo];
            float* dst = v_out + ((size_t)b * C + oo) * NPIX + nb;
            float4 r;
            float y;
            y = (acc[i][0] - rm) * sc + bb; r.x = y / (1.0f + expf(-y));
            y = (acc[i][1] - rm) * sc + bb; r.y = y / (1.0f + expf(-y));
            y = (acc[i][2] - rm) * sc + bb; r.z = y / (1.0f + expf(-y));
            y = (acc[i][3] - rm) * sc + bb; r.w = y / (1.0f + expf(-y));
            *(float4*)&dst[tx4] = r;
        }
    }
}

// ---------------------------------------------------------------------------
// Kernel 2: 3x3 conv (SAME) as implicit GEMM + BN + SiLU.
// ---------------------------------------------------------------------------
__global__ __launch_bounds__(256) void k_conv3(
    const float* __restrict__ vin, const float* __restrict__ pe_w,
    const float* __restrict__ pe_g, const float* __restrict__ pe_b,
    const float* __restrict__ pe_rm, const float* __restrict__ pe_rv,
    float* __restrict__ pp)
{
    __shared__ float As3[16][64][3];  // [c][o][dx]
    __shared__ float Bsh[16][66];     // [c][x+1] with halo
    const int t  = threadIdx.x;
    const int tx = t & 15, ty = t >> 4;
    const int tx4 = tx * 4, ty4 = ty * 4;
    const int y  = blockIdx.x;
    const int ob = blockIdx.y * 64;
    const int b  = blockIdx.z;
    const float* vb = vin + (size_t)b * C * NPIX;

    float acc[4][4] = {};

    for (int dy = 0; dy < 3; ++dy) {
        int yy = y + dy - 1;
        if (yy < 0 || yy >= 64) continue;
        for (int c0 = 0; c0 < C; c0 += 16) {
            #pragma unroll
            for (int e = 0; e < 12; ++e) {
                int idx = e * 256 + t;
                int dx = idx % 3;
                int ol = (idx / 3) & 63;
                int kl = idx / 192;
                As3[kl][ol][dx] =
                    pe_w[((size_t)(ob + ol) * C + c0 + kl) * 9 + dy * 3 + dx];
            }
            for (int idx = t; idx < 16 * 66; idx += 256) {
                int xl = idx % 66, kl = idx / 66;
                int xx = xl - 1;
                Bsh[kl][xl] = (xx >= 0 && xx < 64)
                                  ? vb[(size_t)(c0 + kl) * NPIX + yy * 64 + xx]
                                  : 0.0f;
            }
            __syncthreads();
            #pragma unroll
            for (int kk = 0; kk < 16; ++kk) {
                float bl[6];
                #pragma unroll
                for (int u = 0; u < 6; ++u) bl[u] = Bsh[kk][tx4 + u];
                #pragma unroll
                for (int i = 0; i < 4; ++i) {
                    const float a0 = As3[kk][ty4 + i][0];
                    const float a1 = As3[kk][ty4 + i][1];
                    const float a2 = As3[kk][ty4 + i][2];
                    #pragma unroll
                    for (int j = 0; j < 4; ++j)
                        acc[i][j] += a0 * bl[j] + a1 * bl[j + 1] + a2 * bl[j + 2];
                }
            }
            __syncthreads();
        }
    }

    #pragma unroll
    for (int i = 0; i < 4; ++i) {
        int o = ob + ty4 + i;
        const float sc = pe_g[o] * rsqrtf(pe_rv[o] + EPS);
        const float rm = pe_rm[o], bb = pe_b[o];
        float* dst = pp + ((size_t)b * C + o) * NPIX + y * 64;
        float4 r;
        float yv;
        yv = (acc[i][0] - rm) * sc + bb; r.x = yv / (1.0f + expf(-yv));
        yv = (acc[i][1] - rm) * sc + bb; r.y = yv / (1.0f + expf(-yv));
        yv = (acc[i][2] - rm) * sc + bb; r.z = yv / (1.0f + expf(-yv));
        yv = (acc[i][3] - rm) * sc + bb; r.w = yv / (1.0f + expf(-yv));
        *(float4*)&dst[tx4] = r;
    }
}

// ---------------------------------------------------------------------------
// Kernel 3: area attention (q/k in bf16, v in f32).
// ---------------------------------------------------------------------------
__global__ __launch_bounds__(256) void k_attn(
    const unsigned short* __restrict__ qk, const float* __restrict__ v,
    float* __restrict__ ao)
{
    __shared__ float Qs[8][64];     // also reused as O transpose buffer
    __shared__ float KVs[64][65];
    __shared__ float Ss[8][1024];
    const int t    = threadIdx.x;
    const int lane = t & 63;
    const int tq   = t >> 6;        // 0..3
    const int i0   = tq * 2, i1 = tq * 2 + 1;
    const int qt = blockIdx.x;      // 0..127
    const int h  = blockIdx.y;      // 0..7
    const int ba = blockIdx.z;      // 0..31
    const int b  = ba >> 2;
    const int n0 = (ba & 3) * 1024;
    const int qb = qt * 8;
    const unsigned short* qkb = qk + (size_t)b * 1024 * NPIX;
    const float* vb = v + (size_t)b * C * NPIX;

    // load Q tile (8 rows x 64 dims)
    #pragma unroll
    for (int e = 0; e < 2; ++e) {
        int idx = e * 256 + t;
        int i = idx & 7, d = idx >> 3;
        Qs[i][d] = bf2f(qkb[(size_t)(h * 64 + d) * NPIX + n0 + qb + i]);
    }

    // pass 1: S = (Q K^T) * scale
    for (int kt = 0; kt < 16; ++kt) {
        __syncthreads();
        #pragma unroll
        for (int e = 0; e < 16; ++e) {
            int idx = e * 256 + t;
            int jl = idx & 63, d = idx >> 6;
            KVs[d][jl] =
                bf2f(qkb[(size_t)(512 + h * 64 + d) * NPIX + n0 + kt * 64 + jl]);
        }
        __syncthreads();
        float s0 = 0.f, s1 = 0.f;
        const float4* q0 = (const float4*)Qs[i0];
        const float4* q1 = (const float4*)Qs[i1];
        #pragma unroll
        for (int c = 0; c < 16; ++c) {
            float4 qa = q0[c], qc = q1[c];
            float kv0 = KVs[4 * c + 0][lane];
            float kv1 = KVs[4 * c + 1][lane];
            float kv2 = KVs[4 * c + 2][lane];
            float kv3 = KVs[4 * c + 3][lane];
            s0 += qa.x * kv0 + qa.y * kv1 + qa.z * kv2 + qa.w * kv3;
            s1 += qc.x * kv0 + qc.y * kv1 + qc.z * kv2 + qc.w * kv3;
        }
        Ss[i0][kt * 64 + lane] = s0 * 0.125f;
        Ss[i1][kt * 64 + lane] = s1 * 0.125f;
    }
    __syncthreads();

    // softmax over each row of 1024 (8 rows, 32 threads each)
    {
        const int r = t >> 5, l32 = t & 31;
        float* row = Ss[r];
        float vals[32];
        float m = -1e30f;
        #pragma unroll
        for (int k = 0; k < 32; ++k) {
            vals[k] = row[l32 + 32 * k];
            m = fmaxf(m, vals[k]);
        }
        #pragma unroll
        for (int off = 16; off; off >>= 1) m = fmaxf(m, __shfl_xor(m, off));
        float sum = 0.f;
        #pragma unroll
        for (int k = 0; k < 32; ++k) {
            vals[k] = expf(vals[k] - m);
            sum += vals[k];
        }
        #pragma unroll
        for (int off = 16; off; off >>= 1) sum += __shfl_xor(sum, off);
        const float inv = 1.0f / sum;
        #pragma unroll
        for (int k = 0; k < 32; ++k) row[l32 + 32 * k] = vals[k] * inv;
    }

    // pass 3: O = P * V^T  (V stored [d][j])
    float o0 = 0.f, o1 = 0.f;
    for (int vt = 0; vt < 16; ++vt) {
        __syncthreads();
        #pragma unroll
        for (int e = 0; e < 16; ++e) {
            int idx = e * 256 + t;
            int jl = idx & 63, d = idx >> 6;
            KVs[d][jl] = vb[(size_t)(h * 64 + d) * NPIX + n0 + vt * 64 + jl];
        }
        __syncthreads();
        const float4* p0 = (const float4*)&Ss[i0][vt * 64];
        const float4* p1 = (const float4*)&Ss[i1][vt * 64];
        #pragma unroll
        for (int c = 0; c < 16; ++c) {
            float4 pa = p0[c], pc = p1[c];
            float v0 = KVs[lane][4 * c + 0];
            float v1 = KVs[lane][4 * c + 1];
            float v2 = KVs[lane][4 * c + 2];
            float v3 = KVs[lane][4 * c + 3];
            o0 += pa.x * v0 + pa.y * v1 + pa.z * v2 + pa.w * v3;
            o1 += pc.x * v0 + pc.y * v1 + pc.z * v2 + pc.w * v3;
        }
    }
    __syncthreads();
    // transpose O through LDS and write (ch-major, contiguous 8-wide in n)
    Qs[i0][lane] = o0;
    Qs[i1][lane] = o1;
    __syncthreads();
    float* aob = ao + (size_t)b * C * NPIX;
    #pragma unroll
    for (int e = 0; e < 2; ++e) {
        int idx = e * 256 + t;
        int nl = idx & 7, cl = idx >> 3;
        aob[(size_t)(h * 64 + cl) * NPIX + n0 + qb + nl] = Qs[nl][cl];
    }
}

// ---------------------------------------------------------------------------
// Kernel 4: final conv1x1 on (attn_out + pp) + BN + SiLU -> d_out
// ---------------------------------------------------------------------------
__global__ __launch_bounds__(256) void k_final(
    const float* __restrict__ ao, const float* __restrict__ pp,
    const float* __restrict__ pr_w, const float* __restrict__ pr_g,
    const float* __restrict__ pr_b, const float* __restrict__ pr_rm,
    const float* __restrict__ pr_rv, float* __restrict__ out)
{
    __shared__ float As[16][65];
    __shared__ float Bs[16][64];
    const int t  = threadIdx.x;
    const int tx = t & 15, ty = t >> 4;
    const int tx4 = tx * 4, ty4 = ty * 4;
    const int nb = blockIdx.x * 64;
    const int ob = blockIdx.y * 64;
    const int b  = blockIdx.z;
    const float* aob = ao + (size_t)b * C * NPIX;
    const float* ppb = pp + (size_t)b * C * NPIX;

    float acc[4][4] = {};

    for (int k0 = 0; k0 < C; k0 += 16) {
        #pragma unroll
        for (int e = 0; e < 4; ++e) {
            int idx = e * 256 + t;
            int kl = idx & 15, ol = idx >> 4;
            As[kl][ol] = pr_w[(size_t)(ob + ol) * C + k0 + kl];
        }
        #pragma unroll
        for (int e = 0; e < 4; ++e) {
            int idx = e * 256 + t;
            int nl = idx & 63, kl = idx >> 6;
            size_t g = (size_t)(k0 + kl) * NPIX + nb + nl;
            Bs[kl][nl] = aob[g] + ppb[g];
        }
        __syncthreads();
        #pragma unroll
        for (int kk = 0; kk < 16; ++kk) {
            const float a0 = As[kk][ty4 + 0];
            const float a1 = As[kk][ty4 + 1];
            const float a2 = As[kk][ty4 + 2];
            const float a3 = As[kk][ty4 + 3];
            const float4 bq = *(const float4*)&Bs[kk][tx4];
            acc[0][0] += a0 * bq.x; acc[0][1] += a0 * bq.y; acc[0][2] += a0 * bq.z; acc[0][3] += a0 * bq.w;
            acc[1][0] += a1 * bq.x; acc[1][1] += a1 * bq.y; acc[1][2] += a1 * bq.z; acc[1][3] += a1 * bq.w;
            acc[2][0] += a2 * bq.x; acc[2][1] += a2 * bq.y; acc[2][2] += a2 * bq.z; acc[2][3] += a2 * bq.w;
            acc[3][0] += a3 * bq.x; acc[3][1] += a3 * bq.y; acc[3][2] += a3 * bq.z; acc[3][3] += a3 * bq.w;
        }
        __syncthreads();
    }

    #pragma unroll
    for (int i = 0; i < 4; ++i) {
        int o = ob + ty4 + i;
        const float sc = pr_g[o] * rsqrtf(pr_rv[o] + EPS);
        const float rm = pr_rm[o], bb = pr_b[o];
        float* dst = out + ((size_t)b * C + o) * NPIX + nb;
        float4 r;
        float y;
        y = (acc[i][0] - rm) * sc + bb; r.x = y / (1.0f + expf(-y));
        y = (acc[i][1] - rm) * sc + bb; r.y = y / (1.0f + expf(-y));
        y = (acc[i][2] - rm) * sc + bb; r.z = y / (1.0f + expf(-y));
        y = (acc[i][3] - rm) * sc + bb; r.w = y / (1.0f + expf(-y));
        *(float4*)&dst[tx4] = r;
    }
}

// ---------------------------------------------------------------------------
extern "C" void kernel_launch(void* const* d_in, const int* in_sizes, int n_in,
                              void* d_out, int out_size, void* d_ws, size_t ws_size,
                              hipStream_t stream)
{
    const float* x     = (const float*)d_in[0];
    const float* qk_w  = (const float*)d_in[1];
    const float* qk_g  = (const float*)d_in[2];
    const float* qk_b  = (const float*)d_in[3];
    const float* qk_rm = (const float*)d_in[4];
    const float* qk_rv = (const float*)d_in[5];
    const float* v_w   = (const float*)d_in[6];
    const float* v_g   = (const float*)d_in[7];
    const float* v_b   = (const float*)d_in[8];
    const float* v_rm  = (const float*)d_in[9];
    const float* v_rv  = (const float*)d_in[10];
    const float* pe_w  = (const float*)d_in[11];
    const float* pe_g  = (const float*)d_in[12];
    const float* pe_b  = (const float*)d_in[13];
    const float* pe_rm = (const float*)d_in[14];
    const float* pe_rv = (const float*)d_in[15];
    const float* pr_w  = (const float*)d_in[16];
    const float* pr_g  = (const float*)d_in[17];
    const float* pr_b  = (const float*)d_in[18];
    const float* pr_rm = (const float*)d_in[19];
    const float* pr_rv = (const float*)d_in[20];

    // Workspace layout (192 MB total):
    //   [0,      64MB) : qk bf16 (8*1024*4096 ushort)  -> later reused as pp f32
    //   [64MB,  128MB) : v f32   (8*512*4096)
    //   [128MB, 192MB) : ao f32  (8*512*4096)
    const size_t NEEDED = 201326592;  // 192 MB
    if (ws_size < NEEDED) return;     // diagnostic: absmax-fail (not crash) if ws too small

    unsigned char* ws = (unsigned char*)d_ws;
    unsigned short* qk_ws = (unsigned short*)ws;
    float* v_ws  = (float*)(ws + 67108864);
    float* ao_ws = (float*)(ws + 134217728);
    float* pp_ws = (float*)ws;         // aliases qk region (dead after k_attn)
    float* out   = (float*)d_out;

    dim3 blk(256);
    k_qkv<<<dim3(64, 24, BATCH), blk, 0, stream>>>(
        x, qk_w, qk_g, qk_b, qk_rm, qk_rv, v_w, v_g, v_b, v_rm, v_rv,
        qk_ws, v_ws);
    k_attn<<<dim3(128, 8, 32), blk, 0, stream>>>(qk_ws, v_ws, ao_ws);
    k_conv3<<<dim3(64, 8, BATCH), blk, 0, stream>>>(
        v_ws, pe_w, pe_g, pe_b, pe_rm, pe_rv, pp_ws);
    k_final<<<dim3(64, 8, BATCH), blk, 0, stream>>>(
        ao_ws, pp_ws, pr_w, pr_g, pr_b, pr_rm, pr_rv, out);
}

// Round 5
// 745.235 us; speedup vs baseline: 20.7958x; 20.7958x over previous
//
#include <hip/hip_runtime.h>
#include <math.h>

#define EPS 1e-5f

typedef __attribute__((ext_vector_type(8))) short bh8;   // 8 x bf16
typedef __attribute__((ext_vector_type(4))) float f4;    // MFMA acc

static __device__ __forceinline__ unsigned short f2bf(float f) {
    union { float f; unsigned int u; } a; a.f = f;
    unsigned int r = a.u + 0x7FFFu + ((a.u >> 16) & 1u);
    return (unsigned short)(r >> 16);
}
static __device__ __forceinline__ float bf2f(unsigned short h) {
    union { unsigned int u; float f; } a; a.u = ((unsigned int)h) << 16;
    return a.f;
}
static __device__ __forceinline__ float silu(float y) { return y / (1.0f + __expf(-y)); }

// swizzle key for BK=32 tiles (4 chunks of 16B per 64B row): 2-way residual conflicts
static __device__ __forceinline__ int key4(int row) { return (row ^ (row >> 2)) & 3; }

// ---------------------------------------------------------------------------
// prep: x [b][c][n] f32 -> x_t [b][n][c] bf16 (64x64 transpose tiles)
// ---------------------------------------------------------------------------
__global__ __launch_bounds__(256) void k_prep_x(const float* __restrict__ x,
                                                unsigned short* __restrict__ xt)
{
    __shared__ float Ld[64][65];
    const int t = threadIdx.x;
    const int nb = blockIdx.x * 64, cb = blockIdx.y * 64, b = blockIdx.z;
    const float* xb = x + ((size_t)b * 512 + cb) * 4096 + nb;
    #pragma unroll
    for (int it = 0; it < 16; ++it) {
        int idx = it * 256 + t;
        int c = idx >> 6, n = idx & 63;
        Ld[c][n] = xb[(size_t)c * 4096 + n];
    }
    __syncthreads();
    unsigned short* xo = xt + ((size_t)b * 4096 + nb) * 512 + cb;
    #pragma unroll
    for (int it = 0; it < 16; ++it) {
        int idx = it * 256 + t;
        int n = idx >> 6, c = idx & 63;
        xo[(size_t)n * 512 + c] = f2bf(Ld[c][n]);
    }
}

// ---------------------------------------------------------------------------
// prep: weights -> bf16.  wqkv[1536][512]; pe_pack[9][512][512]; pr[512][512]
// ---------------------------------------------------------------------------
__global__ __launch_bounds__(256) void k_prep_w(
    const float* __restrict__ qk_w, const float* __restrict__ v_w,
    const float* __restrict__ pe_w, const float* __restrict__ pr_w,
    unsigned short* __restrict__ wqkv, unsigned short* __restrict__ pe_p,
    unsigned short* __restrict__ prb)
{
    int i = blockIdx.x * 256 + threadIdx.x;
    if (i < 786432) {
        int o = i >> 9, c = i & 511;
        float v = (o < 1024) ? qk_w[(size_t)o * 512 + c]
                             : v_w[(size_t)(o - 1024) * 512 + c];
        wqkv[i] = f2bf(v);
    }
    if (i < 2359296) {
        int g = i >> 18, rem = i & 262143;
        int o = rem >> 9, c = rem & 511;
        pe_p[i] = f2bf(pe_w[((size_t)o * 512 + c) * 9 + g]);
    }
    if (i < 262144) prb[i] = f2bf(pr_w[i]);
}

// ---------------------------------------------------------------------------
// Kernel 1: qk+v conv1x1 GEMM (MFMA) + BN + SiLU.
//   D[n][o] = sum_c x_t[n][c] * W[o][c];  M=n(128) N=o(128) BK=32, 4 waves.
// ---------------------------------------------------------------------------
__global__ __launch_bounds__(256) void k_qkv(
    const unsigned short* __restrict__ xt, const unsigned short* __restrict__ wqkv,
    const float* __restrict__ qk_g, const float* __restrict__ qk_b,
    const float* __restrict__ qk_rm, const float* __restrict__ qk_rv,
    const float* __restrict__ v_g, const float* __restrict__ v_b,
    const float* __restrict__ v_rm, const float* __restrict__ v_rv,
    unsigned short* __restrict__ qk_t, unsigned short* __restrict__ v_t)
{
    __shared__ unsigned short Al[128 * 32];
    __shared__ unsigned short Bl[128 * 32];
    const int t = threadIdx.x, lane = t & 63, w = t >> 6;
    const int wm = w >> 1, wn = w & 1, lg = lane >> 4, l15 = lane & 15;
    const int nb = blockIdx.x * 128, ob = blockIdx.y * 128, b = blockIdx.z;

    const unsigned short* Ab = xt + ((size_t)b * 4096 + nb) * 512;
    const unsigned short* Bb = wqkv + (size_t)ob * 512;

    f4 acc[4][4];
    #pragma unroll
    for (int i = 0; i < 4; ++i)
        #pragma unroll
        for (int j = 0; j < 4; ++j) acc[i][j] = (f4){0.f, 0.f, 0.f, 0.f};

    for (int k0 = 0; k0 < 512; k0 += 32) {
        __syncthreads();
        #pragma unroll
        for (int it = 0; it < 2; ++it) {
            int ci = it * 256 + t;
            int row = ci >> 2, c = ci & 3;
            bh8 va = *(const bh8*)(Ab + (size_t)row * 512 + k0 + c * 8);
            *(bh8*)&Al[row * 32 + (c ^ key4(row)) * 8] = va;
            bh8 vb = *(const bh8*)(Bb + (size_t)row * 512 + k0 + c * 8);
            *(bh8*)&Bl[row * 32 + (c ^ key4(row)) * 8] = vb;
        }
        __syncthreads();
        bh8 af[4], bf[4];
        #pragma unroll
        for (int mi = 0; mi < 4; ++mi) {
            int row = wm * 64 + mi * 16 + l15;
            af[mi] = *(const bh8*)&Al[row * 32 + (lg ^ key4(row)) * 8];
        }
        #pragma unroll
        for (int ni = 0; ni < 4; ++ni) {
            int row = wn * 64 + ni * 16 + l15;
            bf[ni] = *(const bh8*)&Bl[row * 32 + (lg ^ key4(row)) * 8];
        }
        #pragma unroll
        for (int mi = 0; mi < 4; ++mi)
            #pragma unroll
            for (int ni = 0; ni < 4; ++ni)
                acc[mi][ni] = __builtin_amdgcn_mfma_f32_16x16x32_bf16(
                    af[mi], bf[ni], acc[mi][ni], 0, 0, 0);
    }

    #pragma unroll
    for (int ni = 0; ni < 4; ++ni) {
        int o = ob + wn * 64 + ni * 16 + l15;
        bool isqk = o < 1024;
        int oo = isqk ? o : (o - 1024);
        float g  = isqk ? qk_g[oo]  : v_g[oo];
        float bb = isqk ? qk_b[oo]  : v_b[oo];
        float rm = isqk ? qk_rm[oo] : v_rm[oo];
        float rv = isqk ? qk_rv[oo] : v_rv[oo];
        float sc = g * rsqrtf(rv + EPS);
        #pragma unroll
        for (int mi = 0; mi < 4; ++mi)
            #pragma unroll
            for (int r = 0; r < 4; ++r) {
                int n = nb + wm * 64 + mi * 16 + lg * 4 + r;
                float y = (acc[mi][ni][r] - rm) * sc + bb;
                unsigned short h = f2bf(silu(y));
                if (isqk) qk_t[((size_t)b * 4096 + n) * 1024 + o] = h;
                else      v_t[((size_t)b * 4096 + n) * 512 + oo] = h;
            }
    }
}

// ---------------------------------------------------------------------------
// Kernel 2: 3x3 conv (MFMA implicit GEMM) + BN + SiLU.
//   Block: 4 y-rows x 64 x  (M=256 px, wave=1 y-row) x 64 o (N).
// ---------------------------------------------------------------------------
__global__ __launch_bounds__(256) void k_conv3(
    const unsigned short* __restrict__ vt, const unsigned short* __restrict__ pe_p,
    const float* __restrict__ pe_g, const float* __restrict__ pe_b,
    const float* __restrict__ pe_rm, const float* __restrict__ pe_rv,
    unsigned short* __restrict__ pp)
{
    __shared__ unsigned short Al[4 * 66 * 32];  // [yrow][x+1][c] swizzled
    __shared__ unsigned short Bl[3 * 64 * 32];  // [dx][o][c] swizzled
    const int t = threadIdx.x, lane = t & 63, w = t >> 6;  // w = yrow
    const int lg = lane >> 4, l15 = lane & 15;
    const int y0 = blockIdx.x * 4, ob = blockIdx.y * 64, b = blockIdx.z;

    // zero halo columns xp=0,65 (once; c0-loop only overwrites xp 1..64)
    if (t < 32) {
        int yr = t >> 3, xp = (t & 4) ? 65 : 0, c = t & 3;
        *(bh8*)&Al[(yr * 66 + xp) * 32 + c * 8] = (bh8){0,0,0,0,0,0,0,0};
    }

    f4 acc[4][4];
    #pragma unroll
    for (int i = 0; i < 4; ++i)
        #pragma unroll
        for (int j = 0; j < 4; ++j) acc[i][j] = (f4){0.f, 0.f, 0.f, 0.f};

    for (int dy = 0; dy < 3; ++dy) {
        for (int c0 = 0; c0 < 512; c0 += 32) {
            __syncthreads();
            #pragma unroll
            for (int it = 0; it < 4; ++it) {   // A: 4 yrow x 64 x x 4 chunks
                int ci = it * 256 + t;
                int yr = ci >> 8, rem = ci & 255;
                int xx = rem >> 2, c = rem & 3;
                int yy = y0 + yr + dy - 1;
                bh8 v = (bh8){0,0,0,0,0,0,0,0};
                if (yy >= 0 && yy < 64)
                    v = *(const bh8*)(vt + ((size_t)b * 4096 + yy * 64 + xx) * 512 + c0 + c * 8);
                int prow = yr * 66 + xx + 1;
                *(bh8*)&Al[prow * 32 + (c ^ key4(prow)) * 8] = v;
            }
            #pragma unroll
            for (int it = 0; it < 3; ++it) {   // B: 3 dx x 64 o x 4 chunks
                int ci = it * 256 + t;
                int dx = ci >> 8, rem = ci & 255;
                int orow = rem >> 2, c = rem & 3;
                bh8 v = *(const bh8*)(pe_p + ((size_t)(dy * 3 + dx) * 512 + ob + orow) * 512 + c0 + c * 8);
                *(bh8*)&Bl[(dx * 64 + orow) * 32 + (c ^ key4(orow)) * 8] = v;
            }
            __syncthreads();
            #pragma unroll
            for (int dx = 0; dx < 3; ++dx) {
                bh8 af[4], bf[4];
                #pragma unroll
                for (int mi = 0; mi < 4; ++mi) {
                    int prow = w * 66 + mi * 16 + l15 + dx;
                    af[mi] = *(const bh8*)&Al[prow * 32 + (lg ^ key4(prow)) * 8];
                }
                #pragma unroll
                for (int ni = 0; ni < 4; ++ni) {
                    int orow = ni * 16 + l15;
                    bf[ni] = *(const bh8*)&Bl[(dx * 64 + orow) * 32 + (lg ^ key4(orow)) * 8];
                }
                #pragma unroll
                for (int mi = 0; mi < 4; ++mi)
                    #pragma unroll
                    for (int ni = 0; ni < 4; ++ni)
                        acc[mi][ni] = __builtin_amdgcn_mfma_f32_16x16x32_bf16(
                            af[mi], bf[ni], acc[mi][ni], 0, 0, 0);
            }
        }
    }

    #pragma unroll
    for (int ni = 0; ni < 4; ++ni) {
        int o = ob + ni * 16 + l15;
        float sc = pe_g[o] * rsqrtf(pe_rv[o] + EPS);
        float rm = pe_rm[o], bb = pe_b[o];
        #pragma unroll
        for (int mi = 0; mi < 4; ++mi)
            #pragma unroll
            for (int r = 0; r < 4; ++r) {
                int x = mi * 16 + lg * 4 + r;
                int pix = (y0 + w) * 64 + x;
                float yv = (acc[mi][ni][r] - rm) * sc + bb;
                pp[((size_t)b * 4096 + pix) * 512 + o] = f2bf(silu(yv));
            }
    }
}

// ---------------------------------------------------------------------------
// Kernel 3: area attention (flash, MFMA).  1 wave = 16 q rows; fuses +pp.
// ---------------------------------------------------------------------------
__global__ __launch_bounds__(256) void k_attn(
    const unsigned short* __restrict__ qk_t, const unsigned short* __restrict__ vt,
    const unsigned short* __restrict__ pp, unsigned short* __restrict__ ao)
{
    __shared__ unsigned short Kl[64 * 64];      // [kpos][d] swizzled (8 chunks)
    __shared__ unsigned short Pl[4][16 * 72];   // per-wave P, 144B rows
    const int t = threadIdx.x, lane = t & 63, w = t >> 6;
    const int lg = lane >> 4, l15 = lane & 15;
    const int qb = blockIdx.x * 64 + w * 16;
    const int h = blockIdx.y, ba = blockIdx.z;
    const int b = ba >> 2, n0 = (ba & 3) * 1024;

    const unsigned short* qkb = qk_t + (size_t)b * 4096 * 1024;
    const unsigned short* vb  = vt + (size_t)b * 4096 * 512;

    bh8 qf[2];
    {
        const unsigned short* qp = qkb + (size_t)(n0 + qb + l15) * 1024 + h * 64 + lg * 8;
        qf[0] = *(const bh8*)(qp);
        qf[1] = *(const bh8*)(qp + 32);
    }
    f4 oacc[4];
    #pragma unroll
    for (int i = 0; i < 4; ++i) oacc[i] = (f4){0.f, 0.f, 0.f, 0.f};
    float mrow[4] = {-1e30f, -1e30f, -1e30f, -1e30f};
    float lrow[4] = {0.f, 0.f, 0.f, 0.f};

    for (int kt = 0; kt < 16; ++kt) {
        __syncthreads();
        #pragma unroll
        for (int it = 0; it < 2; ++it) {   // K tile: 64 rows x 8 chunks
            int ci = it * 256 + t;
            int row = ci >> 3, c = ci & 7;
            bh8 v = *(const bh8*)(qkb + (size_t)(n0 + kt * 64 + row) * 1024 + 512 + h * 64 + c * 8);
            *(bh8*)&Kl[row * 64 + (c ^ (row & 7)) * 8] = v;
        }
        __syncthreads();

        // S = Q K^T (raw)
        f4 s[4];
        #pragma unroll
        for (int nt = 0; nt < 4; ++nt) {
            int kr = nt * 16 + l15;
            bh8 kf0 = *(const bh8*)&Kl[kr * 64 + ((lg    ) ^ (kr & 7)) * 8];
            bh8 kf1 = *(const bh8*)&Kl[kr * 64 + ((lg + 4) ^ (kr & 7)) * 8];
            f4 a = (f4){0.f, 0.f, 0.f, 0.f};
            a = __builtin_amdgcn_mfma_f32_16x16x32_bf16(qf[0], kf0, a, 0, 0, 0);
            a = __builtin_amdgcn_mfma_f32_16x16x32_bf16(qf[1], kf1, a, 0, 0, 0);
            s[nt] = a;
        }

        // V fragments (strided u16 global loads; latency hidden under softmax)
        bh8 vf[2][4];
        #pragma unroll
        for (int kg = 0; kg < 2; ++kg)
            #pragma unroll
            for (int nt = 0; nt < 4; ++nt) {
                const unsigned short* vp =
                    vb + (size_t)(n0 + kt * 64 + kg * 32 + lg * 8) * 512 + h * 64 + nt * 16 + l15;
                bh8 vv;
                #pragma unroll
                for (int j = 0; j < 8; ++j) vv[j] = (short)vp[(size_t)j * 512];
                vf[kg][nt] = vv;
            }

        // online softmax
        float mnew[4], alpha[4];
        #pragma unroll
        for (int r = 0; r < 4; ++r) {
            float mx = fmaxf(fmaxf(s[0][r], s[1][r]), fmaxf(s[2][r], s[3][r]));
            mx = fmaxf(mx, __shfl_xor(mx, 1));
            mx = fmaxf(mx, __shfl_xor(mx, 2));
            mx = fmaxf(mx, __shfl_xor(mx, 4));
            mx = fmaxf(mx, __shfl_xor(mx, 8));
            mx *= 0.125f;
            mnew[r] = fmaxf(mrow[r], mx);
            alpha[r] = __expf(mrow[r] - mnew[r]);
            mrow[r] = mnew[r];
        }
        #pragma unroll
        for (int r = 0; r < 4; ++r) {
            float rs = 0.f;
            #pragma unroll
            for (int nt = 0; nt < 4; ++nt) {
                float p = __expf(s[nt][r] * 0.125f - mnew[r]);
                unsigned short ph = f2bf(p);
                rs += bf2f(ph);
                Pl[w][(lg * 4 + r) * 72 + nt * 16 + l15] = ph;
            }
            rs += __shfl_xor(rs, 1); rs += __shfl_xor(rs, 2);
            rs += __shfl_xor(rs, 4); rs += __shfl_xor(rs, 8);
            lrow[r] = lrow[r] * alpha[r] + rs;
            #pragma unroll
            for (int nt = 0; nt < 4; ++nt) oacc[nt][r] *= alpha[r];
        }
        __syncthreads();

        // O += P V
        #pragma unroll
        for (int kg = 0; kg < 2; ++kg) {
            bh8 pf = *(const bh8*)&Pl[w][l15 * 72 + (lg + 4 * kg) * 8];
            #pragma unroll
            for (int nt = 0; nt < 4; ++nt)
                oacc[nt] = __builtin_amdgcn_mfma_f32_16x16x32_bf16(
                    pf, vf[kg][nt], oacc[nt], 0, 0, 0);
        }
    }

    #pragma unroll
    for (int r = 0; r < 4; ++r) {
        float inv = 1.0f / lrow[r];
        int q = n0 + qb + lg * 4 + r;
        #pragma unroll
        for (int nt = 0; nt < 4; ++nt) {
            int d = nt * 16 + l15;
            size_t idx = ((size_t)b * 4096 + q) * 512 + h * 64 + d;
            float val = oacc[nt][r] * inv + bf2f(pp[idx]);
            ao[idx] = f2bf(val);
        }
    }
}

// ---------------------------------------------------------------------------
// Kernel 4: final conv1x1 (MFMA) + BN + SiLU -> d_out (f32, ch-major).
//   M=o(128) N=n(128); stores coalesced dwords along n.
// ---------------------------------------------------------------------------
__global__ __launch_bounds__(256) void k_final(
    const unsigned short* __restrict__ ao, const unsigned short* __restrict__ prw,
    const float* __restrict__ pr_g, const float* __restrict__ pr_b,
    const float* __restrict__ pr_rm, const float* __restrict__ pr_rv,
    float* __restrict__ out)
{
    __shared__ unsigned short Al[128 * 32];
    __shared__ unsigned short Bl[128 * 32];
    const int t = threadIdx.x, lane = t & 63, w = t >> 6;
    const int wm = w >> 1, wn = w & 1, lg = lane >> 4, l15 = lane & 15;
    const int nb = blockIdx.x * 128, ob = blockIdx.y * 128, b = blockIdx.z;

    const unsigned short* Ab = prw + (size_t)ob * 512;
    const unsigned short* Bb = ao + ((size_t)b * 4096 + nb) * 512;

    f4 acc[4][4];
    #pragma unroll
    for (int i = 0; i < 4; ++i)
        #pragma unroll
        for (int j = 0; j < 4; ++j) acc[i][j] = (f4){0.f, 0.f, 0.f, 0.f};

    for (int k0 = 0; k0 < 512; k0 += 32) {
        __syncthreads();
        #pragma unroll
        for (int it = 0; it < 2; ++it) {
            int ci = it * 256 + t;
            int row = ci >> 2, c = ci & 3;
            bh8 va = *(const bh8*)(Ab + (size_t)row * 512 + k0 + c * 8);
            *(bh8*)&Al[row * 32 + (c ^ key4(row)) * 8] = va;
            bh8 vb = *(const bh8*)(Bb + (size_t)row * 512 + k0 + c * 8);
            *(bh8*)&Bl[row * 32 + (c ^ key4(row)) * 8] = vb;
        }
        __syncthreads();
        bh8 af[4], bf[4];
        #pragma unroll
        for (int mi = 0; mi < 4; ++mi) {
            int row = wm * 64 + mi * 16 + l15;
            af[mi] = *(const bh8*)&Al[row * 32 + (lg ^ key4(row)) * 8];
        }
        #pragma unroll
        for (int ni = 0; ni < 4; ++ni) {
            int row = wn * 64 + ni * 16 + l15;
            bf[ni] = *(const bh8*)&Bl[row * 32 + (lg ^ key4(row)) * 8];
        }
        #pragma unroll
        for (int mi = 0; mi < 4; ++mi)
            #pragma unroll
            for (int ni = 0; ni < 4; ++ni)
                acc[mi][ni] = __builtin_amdgcn_mfma_f32_16x16x32_bf16(
                    af[mi], bf[ni], acc[mi][ni], 0, 0, 0);
    }

    #pragma unroll
    for (int mi = 0; mi < 4; ++mi)
        #pragma unroll
        for (int r = 0; r < 4; ++r) {
            int o = ob + wm * 64 + mi * 16 + lg * 4 + r;
            float sc = pr_g[o] * rsqrtf(pr_rv[o] + EPS);
            float rm = pr_rm[o], bb = pr_b[o];
            #pragma unroll
            for (int ni = 0; ni < 4; ++ni) {
                int n = nb + wn * 64 + ni * 16 + l15;
                float y = (acc[mi][ni][r] - rm) * sc + bb;
                out[((size_t)b * 512 + o) * 4096 + n] = silu(y);
            }
        }
}

// ---------------------------------------------------------------------------
extern "C" void kernel_launch(void* const* d_in, const int* in_sizes, int n_in,
                              void* d_out, int out_size, void* d_ws, size_t ws_size,
                              hipStream_t stream)
{
    const float* x     = (const float*)d_in[0];
    const float* qk_w  = (const float*)d_in[1];
    const float* qk_g  = (const float*)d_in[2];
    const float* qk_b  = (const float*)d_in[3];
    const float* qk_rm = (const float*)d_in[4];
    const float* qk_rv = (const float*)d_in[5];
    const float* v_w   = (const float*)d_in[6];
    const float* v_g   = (const float*)d_in[7];
    const float* v_b   = (const float*)d_in[8];
    const float* v_rm  = (const float*)d_in[9];
    const float* v_rv  = (const float*)d_in[10];
    const float* pe_w  = (const float*)d_in[11];
    const float* pe_g  = (const float*)d_in[12];
    const float* pe_b  = (const float*)d_in[13];
    const float* pe_rm = (const float*)d_in[14];
    const float* pe_rv = (const float*)d_in[15];
    const float* pr_w  = (const float*)d_in[16];
    const float* pr_g  = (const float*)d_in[17];
    const float* pr_b  = (const float*)d_in[18];
    const float* pr_rm = (const float*)d_in[19];
    const float* pr_rv = (const float*)d_in[20];

    // Workspace layout (bytes):
    //   0        : x_t bf16 [8][4096][512]   (32MB)  -- reused as pp after qkv
    //   32MB     : qk_t bf16 [8][4096][1024] (64MB)
    //   96MB     : v_t bf16 [8][4096][512]   (32MB)
    //   128MB    : ao bf16  [8][4096][512]   (32MB)
    //   160MB    : wqkv bf16 [1536][512]     (1.5MB)
    //   +        : pe_pack bf16 [9][512][512](4.5MB)
    //   +        : pr bf16 [512][512]        (0.5MB)
    const size_t NEEDED = 174587904;
    if (ws_size < NEEDED) return;

    unsigned char* ws = (unsigned char*)d_ws;
    unsigned short* x_t   = (unsigned short*)ws;
    unsigned short* pp_ws = (unsigned short*)ws;                  // alias (x_t dead)
    unsigned short* qk_ws = (unsigned short*)(ws + 33554432);
    unsigned short* v_ws  = (unsigned short*)(ws + 100663296);
    unsigned short* ao_ws = (unsigned short*)(ws + 134217728);
    unsigned short* wqkv  = (unsigned short*)(ws + 167772160);
    unsigned short* pe_p  = (unsigned short*)(ws + 169345024);
    unsigned short* pr_bw = (unsigned short*)(ws + 174063616);
    float* out = (float*)d_out;

    dim3 blk(256);
    k_prep_x<<<dim3(64, 8, 8), blk, 0, stream>>>(x, x_t);
    k_prep_w<<<dim3(9216), blk, 0, stream>>>(qk_w, v_w, pe_w, pr_w, wqkv, pe_p, pr_bw);
    k_qkv<<<dim3(32, 12, 8), blk, 0, stream>>>(
        x_t, wqkv, qk_g, qk_b, qk_rm, qk_rv, v_g, v_b, v_rm, v_rv, qk_ws, v_ws);
    k_conv3<<<dim3(16, 8, 8), blk, 0, stream>>>(
        v_ws, pe_p, pe_g, pe_b, pe_rm, pe_rv, pp_ws);
    k_attn<<<dim3(16, 8, 32), blk, 0, stream>>>(qk_ws, v_ws, pp_ws, ao_ws);
    k_final<<<dim3(32, 4, 8), blk, 0, stream>>>(
        ao_ws, pr_bw, pr_g, pr_b, pr_rm, pr_rv, out);
}